// Round 1
// baseline (1376.994 us; speedup 1.0000x reference)
//
#include <hip/hip_runtime.h>
#include <math.h>

#define FOUT 128
#define TILE_M 64
#define TILE_K 64
#define BS_STRIDE 132  // 128 + 4 pad: breaks the k-row stride == 0 mod 32-banks alias

// C[r][c] = sum_k A[r][c?]: macro tile 64 rows x 128 cols, K-tiled by 64.
// DO_LIF=false: plain GEMM (support = x @ W), writes C.
// DO_LIF=true : I = A@B + bias, then 5-step adaptive-LIF recurrence, writes mean spikes.
template<bool DO_LIF>
__global__ __launch_bounds__(256, 2) void gemm_tile_kernel(
    const float* __restrict__ A,    // rows [batch*M + r], row stride K
    const float* __restrict__ Bm,   // per-batch [K][FOUT]
    const float* __restrict__ bias, // [FOUT] (LIF only)
    const int* __restrict__ tsp,    // time_steps (LIF only)
    float* __restrict__ out,        // [batch*M][FOUT]
    int K, int M) {
  __shared__ float aT[TILE_K][TILE_M];      // transposed A tile, 16 KB
  __shared__ float bs[TILE_K][BS_STRIDE];   // B tile, ~33 KB

  const int tid = threadIdx.x;
  const int batch = blockIdx.y;
  const long long n0 = (long long)blockIdx.x * TILE_M;
  const float* Ab = A + ((long long)batch * M + n0) * K;
  const float* Bb = Bm + (long long)batch * K * FOUT;

  const int tx = tid & 15;   // col group: cols tx*8 .. tx*8+7
  const int ty = tid >> 4;   // row group: rows ty*4 .. ty*4+3

  float acc[4][8] = {};

  // staging assignments
  const int ar = tid & 63;          // A: row within tile
  const int ak = (tid >> 6) * 16;   // A: k offset (4 float4)
  const int bk = tid >> 2;          // B: k row within tile
  const int bc = (tid & 3) * 32;    // B: col offset (8 float4)

  for (int k0 = 0; k0 < K; k0 += TILE_K) {
    // ---- stage A tile (transposed into LDS) ----
    const float4* asrc = (const float4*)(Ab + (long long)ar * K + k0 + ak);
    #pragma unroll
    for (int j = 0; j < 4; ++j) {
      float4 v = asrc[j];
      aT[ak + 4*j + 0][ar] = v.x;
      aT[ak + 4*j + 1][ar] = v.y;
      aT[ak + 4*j + 2][ar] = v.z;
      aT[ak + 4*j + 3][ar] = v.w;
    }
    // ---- stage B tile ----
    const float4* bsrc = (const float4*)(Bb + (long long)(k0 + bk) * FOUT + bc);
    #pragma unroll
    for (int j = 0; j < 8; ++j) {
      *(float4*)&bs[bk][bc + 4*j] = bsrc[j];
    }
    __syncthreads();

    // ---- compute: 4x8 outer product per k ----
    #pragma unroll 16
    for (int k = 0; k < TILE_K; ++k) {
      float a[4], bb[8];
      *(float4*)a       = *(const float4*)&aT[k][ty*4];
      *(float4*)&bb[0]  = *(const float4*)&bs[k][tx*8];
      *(float4*)&bb[4]  = *(const float4*)&bs[k][tx*8 + 4];
      #pragma unroll
      for (int i = 0; i < 4; ++i)
        #pragma unroll
        for (int j = 0; j < 8; ++j)
          acc[i][j] = fmaf(a[i], bb[j], acc[i][j]);
    }
    __syncthreads();
  }

  // ---- epilogue ----
  if (DO_LIF) {
    const int T = *tsp;
    const float mem_decay = 0.95f;  // 1 - 1/20
    #pragma unroll
    for (int i = 0; i < 4; ++i) {
      float res[8];
      #pragma unroll
      for (int j = 0; j < 8; ++j) {
        float I = acc[i][j] + bias[tx*8 + j];
        float v = 0.0f, th = 1.0f, s_acc = 0.0f;
        for (int t = 0; t < T; ++t) {
          v = v * mem_decay + I;                 // leaky integrate
          float u = v - th;
          float sig = 1.0f / (1.0f + expf(-4.0f * u));
          float hard = (u >= 0.0f) ? 1.0f : 0.0f;
          float s = (hard - sig) + sig;          // straight-through forward value
          s_acc += s;
          v = v * (1.0f - s);                    // reset on spike
          th = th + (1.0f - th) / 60.0f + 0.1f * s;  // adaptive threshold
        }
        res[j] = s_acc / (float)T;
      }
      long long row = (long long)batch * M + n0 + ty*4 + i;
      float* orow = out + row * FOUT + tx*8;
      *(float4*)&orow[0] = *(float4*)&res[0];
      *(float4*)&orow[4] = *(float4*)&res[4];
    }
  } else {
    #pragma unroll
    for (int i = 0; i < 4; ++i) {
      long long row = (long long)batch * M + n0 + ty*4 + i;
      float* orow = out + row * FOUT + tx*8;
      *(float4*)&orow[0] = *(float4*)&acc[i][0];
      *(float4*)&orow[4] = *(float4*)&acc[i][4];
    }
  }
}

extern "C" void kernel_launch(void* const* d_in, const int* in_sizes, int n_in,
                              void* d_out, int out_size, void* d_ws, size_t ws_size,
                              hipStream_t stream) {
  const float* x    = (const float*)d_in[0];
  const float* adj  = (const float*)d_in[1];
  const float* w    = (const float*)d_in[2];
  const float* bias = (const float*)d_in[3];
  const int*   tsp  = (const int*)d_in[4];
  float* out = (float*)d_out;
  float* support = (float*)d_ws;  // needs B*N*FOUT*4 = 8 MB of scratch

  // derive shapes: in_sizes[0] = B*N*F, in_sizes[1] = B*N*N
  const long long sz_x = in_sizes[0];
  const long long sz_adj = in_sizes[1];
  const int N = (int)(sz_adj / sz_x * FOUT);       // (B*N*N)/(B*N*F)*F
  const int B = (int)(sz_x / ((long long)N * FOUT));
  const int rows = B * N;

  // support = x @ W   (rows x 128, K=128)
  gemm_tile_kernel<false><<<dim3(rows / TILE_M, 1), 256, 0, stream>>>(
      x, w, nullptr, nullptr, support, FOUT, rows);

  // out = LIF(adj @ support + bias)  (per batch: 8192x128, K=8192)
  gemm_tile_kernel<true><<<dim3(N / TILE_M, B), 256, 0, stream>>>(
      adj, support, bias, tsp, out, N, N);
}

// Round 2
// 734.689 us; speedup vs baseline: 1.8743x; 1.8743x over previous
//
#include <hip/hip_runtime.h>
#include <math.h>

typedef __attribute__((ext_vector_type(8))) short short8;
typedef __attribute__((ext_vector_type(4))) float f32x4;

// fp32 -> bf16 bits, round-to-nearest-even
static __device__ __forceinline__ unsigned short f2bf(float f) {
  unsigned int u = __float_as_uint(f);
  u = u + 0x7fffu + ((u >> 16) & 1u);
  return (unsigned short)(u >> 16);
}

// ---------------- kernel 1: supT[batch][col][n] (bf16) = (x @ W)^T ----------------
// tile 64 rows x 128 cols, fp32 VALU (tiny: 0.5 GFLOP)
__global__ __launch_bounds__(256) void support_kernel(
    const float* __restrict__ x, const float* __restrict__ w,
    unsigned short* __restrict__ supT, int N) {
  __shared__ float aT[64][65];    // transposed x tile (+1 pad)
  __shared__ float bs[64][132];   // W tile (+4 pad)

  const int tid = threadIdx.x;
  const long long r0 = (long long)blockIdx.x * 64;
  const float* Ab = x + r0 * 128;
  const int tx = tid & 15;        // col group: cols tx*8..+7
  const int ty = tid >> 4;        // row group: rows ty*4..+3

  float acc[4][8] = {};
  const int ar = tid & 63, ak = (tid >> 6) * 16;
  const int bk = tid >> 2, bc = (tid & 3) * 32;

  for (int k0 = 0; k0 < 128; k0 += 64) {
    const float4* asrc = (const float4*)(Ab + (long long)ar * 128 + k0 + ak);
    #pragma unroll
    for (int j = 0; j < 4; ++j) {
      float4 v = asrc[j];
      aT[ak + 4*j + 0][ar] = v.x;
      aT[ak + 4*j + 1][ar] = v.y;
      aT[ak + 4*j + 2][ar] = v.z;
      aT[ak + 4*j + 3][ar] = v.w;
    }
    const float4* bsrc = (const float4*)(w + (long long)(k0 + bk) * 128 + bc);
    #pragma unroll
    for (int j = 0; j < 8; ++j) *(float4*)&bs[bk][bc + 4*j] = bsrc[j];
    __syncthreads();
    #pragma unroll 16
    for (int k = 0; k < 64; ++k) {
      float a[4], b[8];
      *(float4*)a      = *(const float4*)&aT[k][ty*4];
      *(float4*)&b[0]  = *(const float4*)&bs[k][tx*8];
      *(float4*)&b[4]  = *(const float4*)&bs[k][tx*8 + 4];
      #pragma unroll
      for (int i = 0; i < 4; ++i)
        #pragma unroll
        for (int j = 0; j < 8; ++j)
          acc[i][j] = fmaf(a[i], b[j], acc[i][j]);
    }
    __syncthreads();
  }
  // write transposed bf16: supT[batch*128*N + col*N + n]
  const int batch = (int)(r0 / N);
  const int nloc = (int)(r0 % N) + ty * 4;
  #pragma unroll
  for (int j = 0; j < 8; ++j) {
    const int col = tx * 8 + j;
    ushort4 pv;
    pv.x = f2bf(acc[0][j]); pv.y = f2bf(acc[1][j]);
    pv.z = f2bf(acc[2][j]); pv.w = f2bf(acc[3][j]);
    *(ushort4*)&supT[(size_t)batch * 128 * N + (size_t)col * N + nloc] = pv;
  }
}

// ---------------- kernel 2: out = LIF(adj @ support + bias) ----------------
// tile 32 rows x 128 cols, K-tile 128. adj staged fp32->bf16 via LDS;
// support fragments read straight from global (L2-resident, 4 MB).
#define BK2 128
#define ASTR (BK2 + 8)   // 136 shorts = 272 B row stride: banks shift 4/row, 16B-aligned

__global__ __launch_bounds__(256) void spike_gemm_kernel(
    const float* __restrict__ adj, const unsigned short* __restrict__ supT,
    const float* __restrict__ bias, const int* __restrict__ tsp,
    float* __restrict__ out, int N) {
  __shared__ __align__(16) unsigned short As[32][ASTR];  // 8704 B

  const int tid = threadIdx.x;
  const int lane = tid & 63;
  const int wave = tid >> 6;           // wave w -> cols w*32..w*32+31
  const int batch = blockIdx.y;
  const int n0 = blockIdx.x * 32;

  const float* Ab = adj + ((size_t)batch * N + n0) * N;
  const unsigned short* Bb = supT + (size_t)batch * 128 * N;

  // A staging: thread -> row (tid>>4) (+16), k-chunk (tid&15)*8
  const int ar = tid >> 4;
  const int akq = tid & 15;

  // MFMA fragment coords (16x16x32): m/n = lane&15, k-group = lane>>4
  const int fm = lane & 15;
  const int kg = lane >> 4;

  f32x4 acc[2][2] = {};   // [row-tile][col-tile]

  for (int k0 = 0; k0 < N; k0 += BK2) {
    // ---- B fragments: direct global->reg (no LDS), 8x b128 in flight ----
    uint4 bfr[2][4];
    #pragma unroll
    for (int ct = 0; ct < 2; ++ct) {
      const unsigned short* bp =
          Bb + (size_t)(wave * 32 + ct * 16 + fm) * N + k0 + kg * 8;
      #pragma unroll
      for (int ks = 0; ks < 4; ++ks)
        bfr[ct][ks] = *(const uint4*)(bp + ks * 32);
    }
    // ---- A tile: global fp32 -> bf16 -> LDS ----
    #pragma unroll
    for (int r = 0; r < 2; ++r) {
      const float* ap = Ab + (size_t)(ar + r * 16) * N + k0 + akq * 8;
      float4 v0 = *(const float4*)ap;
      float4 v1 = *(const float4*)(ap + 4);
      ushort4 p0, p1;
      p0.x = f2bf(v0.x); p0.y = f2bf(v0.y); p0.z = f2bf(v0.z); p0.w = f2bf(v0.w);
      p1.x = f2bf(v1.x); p1.y = f2bf(v1.y); p1.z = f2bf(v1.z); p1.w = f2bf(v1.w);
      ushort4* dst = (ushort4*)&As[ar + r * 16][akq * 8];
      dst[0] = p0; dst[1] = p1;
    }
    __syncthreads();
    // ---- MFMA: 4 k-steps of 32 ----
    #pragma unroll
    for (int ks = 0; ks < 4; ++ks) {
      short8 a0 = *(const short8*)&As[fm][ks * 32 + kg * 8];
      short8 a1 = *(const short8*)&As[16 + fm][ks * 32 + kg * 8];
      #pragma unroll
      for (int ct = 0; ct < 2; ++ct) {
        short8 b = *(const short8*)&bfr[ct][ks];
        acc[0][ct] = __builtin_amdgcn_mfma_f32_16x16x32_bf16(a0, b, acc[0][ct], 0, 0, 0);
        acc[1][ct] = __builtin_amdgcn_mfma_f32_16x16x32_bf16(a1, b, acc[1][ct], 0, 0, 0);
      }
    }
    __syncthreads();
  }

  // ---- epilogue: adaptive-LIF recurrence, exact reference op order ----
  const int T = *tsp;
  #pragma unroll
  for (int rt = 0; rt < 2; ++rt) {
    #pragma unroll
    for (int ct = 0; ct < 2; ++ct) {
      const int col = wave * 32 + ct * 16 + fm;
      const float bv = bias[col];
      #pragma unroll
      for (int i = 0; i < 4; ++i) {
        float I = acc[rt][ct][i] + bv;
        float v = 0.0f, th = 1.0f, sacc = 0.0f;
        for (int t = 0; t < T; ++t) {
          v = v * 0.95f + I;                       // 1 - 1/tau_mem
          float u = v - th;
          float sig = 1.0f / (1.0f + expf(-4.0f * u));
          float hard = (u >= 0.0f) ? 1.0f : 0.0f;
          float s = (hard - sig) + sig;            // straight-through fwd
          sacc += s;
          v = v * (1.0f - s);
          th = th + (1.0f - th) / 60.0f + 0.1f * s;
        }
        const int row = n0 + rt * 16 + kg * 4 + i;
        out[((size_t)batch * N + row) * 128 + col] = sacc / (float)T;
      }
    }
  }
}

extern "C" void kernel_launch(void* const* d_in, const int* in_sizes, int n_in,
                              void* d_out, int out_size, void* d_ws, size_t ws_size,
                              hipStream_t stream) {
  const float* x    = (const float*)d_in[0];
  const float* adj  = (const float*)d_in[1];
  const float* w    = (const float*)d_in[2];
  const float* bias = (const float*)d_in[3];
  const int*   tsp  = (const int*)d_in[4];
  float* out = (float*)d_out;
  unsigned short* supT = (unsigned short*)d_ws;  // 2*128*8192*2B = 4 MB

  const long long sz_x = in_sizes[0];
  const long long sz_adj = in_sizes[1];
  const int N = (int)(sz_adj / sz_x * 128);
  const int B = (int)(sz_x / ((long long)N * 128));
  const int rows = B * N;

  support_kernel<<<rows / 64, 256, 0, stream>>>(x, w, supT, N);
  spike_gemm_kernel<<<dim3(N / 32, B), 256, 0, stream>>>(adj, supT, bias, tsp, out, N);
}